// Round 16
// baseline (171.588 us; speedup 1.0000x reference)
//
#include <hip/hip_runtime.h>
#include <cstdint>

#define N_TOK 2048
#define CDIM  1024
#define NEXP  16
#define TOPK  2
#define HDIM  1024
#define SDIM  2048
#define ESLOT 48
#define GU_EXP_BLOCKS (ESLOT * 16)              // 768
#define GU_SH_BLOCKS  (16 * 32)                 // 512
#define GU_NWG (GU_EXP_BLOCKS + GU_SH_BLOCKS)   // 1280 (GEMM portion)
#define DW_CONV_BLOCKS 4096                     // flat dw convert, 4096 el/block
#define GU9X_NWG (GU_NWG + DW_CONV_BLOCKS)      // 5376
#define DN_EXP_BLOCKS (ESLOT * 8)               // 384
#define DN_SH_BLOCKS  (16 * 8)                  // 128
#define DN_NWG (DN_EXP_BLOCKS + DN_SH_BLOCKS)   // 512
#define PREP_GUW_BLKS 16384                     // 33.55M el / 2048
#define PREP_SH_BLKS  1536                      // 3 x 512 transpose tiles
#define PREP_NWG (1 + PREP_GUW_BLKS + PREP_SH_BLKS)

typedef __bf16 bf16;
typedef __bf16 bf16x8 __attribute__((ext_vector_type(8)));
typedef float  f32x4  __attribute__((ext_vector_type(4)));
typedef unsigned int u32;
typedef u32 u32x2 __attribute__((ext_vector_type(2)));
typedef unsigned short u16;

typedef __attribute__((address_space(3))) uint32_t lds_u32_t;
typedef __attribute__((address_space(1))) uint32_t glb_u32_t;

union FragU { u32 w[4]; bf16x8 v; };

__device__ __forceinline__ void gload16(const void* g, void* l) {
  __builtin_amdgcn_global_load_lds((const glb_u32_t*)(uintptr_t)g,
                                   (lds_u32_t*)(uintptr_t)l, 16, 0, 0);
}
__device__ __forceinline__ float fromb(u16 s) {
  union { float f; u32 u; } z; z.u = ((u32)s) << 16; return z.f;
}
__device__ __forceinline__ int xcd_swz(int bid, int nwg) {
  return (bid & 7) * (nwg >> 3) + (bid >> 3);
}
#define SBAR0() __builtin_amdgcn_sched_barrier(0)
#define WAIT_VM(N) do { asm volatile("s_waitcnt vmcnt(" #N ")" ::: "memory"); \
                        SBAR0(); } while (0)
#define WAIT_LGKM0() do { asm volatile("s_waitcnt lgkmcnt(0)" ::: "memory"); \
                          SBAR0(); } while (0)

// 64x64 transpose-convert tile: src [K][N] fp32 -> dst [N][K] bf16
__device__ __forceinline__ void conv_tile(const float* __restrict__ s,
                                          bf16* __restrict__ d,
                                          int K, int N, int k0, int n0,
                                          int t, float* ld) {
  const int kk = t >> 4, c4 = (t & 15) * 4;
#pragma unroll
  for (int q = 0; q < 4; ++q) {
    float4 f = *(const float4*)(s + (size_t)(k0 + kk + q * 16) * N + n0 + c4);
    float* lp = &ld[(kk + q * 16) * 68 + c4];
    lp[0] = f.x; lp[1] = f.y; lp[2] = f.z; lp[3] = f.w;
  }
  __syncthreads();
  const int nn = t >> 2, kc = (t & 3) * 16;
  bf16x8 v0, v1;
#pragma unroll
  for (int j = 0; j < 8; ++j) {
    v0[j] = (bf16)ld[(kc + j) * 68 + nn];
    v1[j] = (bf16)ld[(kc + 8 + j) * 68 + nn];
  }
  bf16* dp = d + (size_t)(n0 + nn) * K + k0 + kc;
  *(bf16x8*)dp = v0;
  *(bf16x8*)(dp + 8) = v1;
}

// ---------------- router (4 tokens/block, fused x->bf16) ----------------
__global__ __launch_bounds__(256)
void router_kernel(const float* __restrict__ x,
                   const float* __restrict__ rw,
                   bf16* __restrict__ xb,
                   int* __restrict__ sel,
                   float* __restrict__ gatew) {
  int n = blockIdx.x * 4 + (threadIdx.x >> 6);
  int lane = threadIdx.x & 63;
  const float* xr = x + (size_t)n * CDIM;
  float xv[16];
#pragma unroll
  for (int q = 0; q < 4; ++q) {
    float4 f = *(const float4*)(xr + lane * 16 + q * 4);
    xv[q * 4 + 0] = f.x; xv[q * 4 + 1] = f.y; xv[q * 4 + 2] = f.z; xv[q * 4 + 3] = f.w;
  }
  bf16x8 v0, v1;
#pragma unroll
  for (int j = 0; j < 8; ++j) { v0[j] = (bf16)xv[j]; v1[j] = (bf16)xv[8 + j]; }
  bf16* xo = xb + (size_t)n * CDIM + lane * 16;
  *(bf16x8*)xo = v0;
  *(bf16x8*)(xo + 8) = v1;
  float acc[NEXP];
#pragma unroll
  for (int e = 0; e < NEXP; ++e) {
    float a = 0.f;
    const float* rwe = rw + e * CDIM + lane * 16;
#pragma unroll
    for (int j = 0; j < 16; ++j) a += xv[j] * rwe[j];
    acc[e] = a;
  }
#pragma unroll
  for (int off = 32; off > 0; off >>= 1) {
#pragma unroll
    for (int e = 0; e < NEXP; ++e) acc[e] += __shfl_xor(acc[e], off, 64);
  }
  if (lane == 0) {
    int i0 = 0; float v0_ = acc[0];
#pragma unroll
    for (int e = 1; e < NEXP; ++e) if (acc[e] > v0_) { v0_ = acc[e]; i0 = e; }
    int i1 = (i0 == 0) ? 1 : 0; float v1_ = acc[i1];
#pragma unroll
    for (int e = 0; e < NEXP; ++e) if (e != i0 && acc[e] > v1_) { v1_ = acc[e]; i1 = e; }
    sel[2 * n] = i0; sel[2 * n + 1] = i1;
    gatew[2 * n]     = 1.f / (1.f + expf(-v0_));
    gatew[2 * n + 1] = 1.f / (1.f + expf(-v1_));
  }
}

// -------- prep: guw flat convert (streaming) + shared transposes + scan -------
__global__ __launch_bounds__(256)
void prep_kernel(const float* __restrict__ guw,
                 const float* __restrict__ sgw,
                 const float* __restrict__ suw,
                 const float* __restrict__ sdw,
                 bf16* __restrict__ guw_bk,    // [E][1024k][2048n] flat
                 bf16* __restrict__ sgw_bk,    // [1024c][2048s]
                 bf16* __restrict__ suw_bk,    // [1024c][2048s]
                 bf16* __restrict__ sdw_bk,    // [2048s][1024c]
                 const int* __restrict__ sel,
                 const float* __restrict__ gatew,
                 int* __restrict__ counts,
                 int* __restrict__ offsets,
                 int* __restrict__ tab128,
                 int* __restrict__ ntiles,
                 int* __restrict__ entry_token,
                 float* __restrict__ entry_gate,
                 int* __restrict__ entry_pos) {
  __shared__ __align__(16) float ld[64 * 68];
  const int b = blockIdx.x;
  const int t = threadIdx.x;
  if (b == 0) {
    int* hist = (int*)ld;
    int* cur = hist + NEXP;
    if (t < NEXP) hist[t] = 0;
    __syncthreads();
    for (int i = t; i < N_TOK * TOPK; i += 256) atomicAdd(&hist[sel[i]], 1);
    __syncthreads();
    if (t == 0) {
      int s = 0, a = 0;
      for (int e = 0; e < NEXP; ++e) {
        int c = hist[e];
        counts[e] = c; offsets[e] = s; cur[e] = s;
        for (int m0 = 0; m0 < c; m0 += 128) tab128[a++] = (e << 16) | m0;
        s += c;
      }
      ntiles[0] = a;
    }
    __syncthreads();
    for (int i = t; i < N_TOK * TOPK; i += 256) {
      int e = sel[i];
      int pos = atomicAdd(&cur[e], 1);
      entry_token[pos] = i >> 1;
      entry_gate[pos] = gatew[i];
      entry_pos[i] = pos;
    }
    return;
  }
  if (b <= PREP_GUW_BLKS) {
    // flat streaming convert of guw (layout preserved, k-major)
    size_t i = (size_t)(b - 1) * 2048 + t * 8;
    float4 f0 = *(const float4*)(guw + i);
    float4 f1 = *(const float4*)(guw + i + 4);
    bf16x8 v;
    v[0]=(bf16)f0.x; v[1]=(bf16)f0.y; v[2]=(bf16)f0.z; v[3]=(bf16)f0.w;
    v[4]=(bf16)f1.x; v[5]=(bf16)f1.y; v[6]=(bf16)f1.z; v[7]=(bf16)f1.w;
    *(bf16x8*)(guw_bk + i) = v;
    return;
  }
  // shared-weight transposes to k-major
  const int b2 = b - 1 - PREP_GUW_BLKS;   // 0..1535
  const int which = b2 >> 9;
  const int tile = b2 & 511;
  if (which == 0) {        // sgw [2048s][1024c] -> [1024c][2048s]
    conv_tile(sgw, sgw_bk, SDIM, CDIM, (tile >> 4) * 64, (tile & 15) * 64, t, ld);
  } else if (which == 1) { // suw
    conv_tile(suw, suw_bk, SDIM, CDIM, (tile >> 4) * 64, (tile & 15) * 64, t, ld);
  } else {                 // sdw [1024c][2048s] -> [2048s][1024c]
    conv_tile(sdw, sdw_bk, CDIM, SDIM, (tile >> 5) * 64, (tile & 31) * 64, t, ld);
  }
}

// ===== GU GEMM (8 waves, BK=64, counted vmcnt, tr-read B) + dw flat convert ====
// B panels are k-major bf16; LDS B layout [np][64k][16n] linear; fragments via
// ds_read_b64_tr_b16. A row-major as before; A frags via 2x ds_read_b64 with the
// matching k-permutation (grp*4 | 16+grp*4).
__global__ __launch_bounds__(512, 2)
void gu10(const bf16* __restrict__ xb,
          const bf16* __restrict__ guw_bk,   // [E][1024k][2048n]
          const bf16* __restrict__ sgw_bk,   // [1024k][2048n]
          const bf16* __restrict__ suw_bk,   // [1024k][2048n]
          bf16* __restrict__ h_exp,
          bf16* __restrict__ h_sh,
          const int* __restrict__ counts,
          const int* __restrict__ offsets,
          const int* __restrict__ entry_token,
          const int* __restrict__ tab128,
          const int* __restrict__ ntiles,
          const float* __restrict__ dw,
          bf16* __restrict__ dw_bk) {
  __shared__ __align__(16) bf16 sA[2 * 8192];    // 32 KB
  __shared__ __align__(16) bf16 sBg[3 * 4096];   // 24 KB, [np][k][16n] per buf
  __shared__ __align__(16) bf16 sBu[3 * 4096];   // 24 KB

  const int t = threadIdx.x;

  // trailing blocks: dw flat streaming convert
  if (blockIdx.x >= GU_NWG) {
    size_t i = (size_t)(blockIdx.x - GU_NWG) * 4096 + t * 8;
    float4 f0 = *(const float4*)(dw + i);
    float4 f1 = *(const float4*)(dw + i + 4);
    bf16x8 v;
    v[0]=(bf16)f0.x; v[1]=(bf16)f0.y; v[2]=(bf16)f0.z; v[3]=(bf16)f0.w;
    v[4]=(bf16)f1.x; v[5]=(bf16)f1.y; v[6]=(bf16)f1.z; v[7]=(bf16)f1.w;
    *(bf16x8*)(dw_bk + i) = v;
    return;
  }

  const int bid = xcd_swz(blockIdx.x, GU_NWG);
  const bool is_exp = bid < GU_EXP_BLOCKS;
  const int wid = t >> 6, lane = t & 63;

  int n0, mguard;
  bf16* hbase; int hstride;
  const bf16 *gbase, *ubase;   // k-major panel bases (row stride 2048)
  const int arow = t >> 3;
  const int sc = (t & 7) ^ (arow & 7);
  const bf16* asrc[2];

  if (is_exp) {
    const int slot = bid >> 4;
    if (slot >= ntiles[0]) return;
    const int packed = tab128[slot];
    const int e = packed >> 16;
    const int m0 = packed & 0xffff;
    const int cnt = counts[e];
    const int base = offsets[e];
    n0 = (bid & 15) * 64;
    mguard = cnt - m0;
#pragma unroll
    for (int i = 0; i < 2; ++i) {
      int r = m0 + i * 64 + arow;
      int tok = entry_token[base + ((r < cnt) ? r : (cnt - 1))];
      asrc[i] = xb + (size_t)tok * CDIM + sc * 8;
    }
    const bf16* we = guw_bk + (size_t)e * CDIM * (2 * HDIM);
    gbase = we + n0;
    ubase = we + HDIM + n0;
    hbase = h_exp + (size_t)(base + m0) * HDIM + n0;
    hstride = HDIM;
  } else {
    const int sid = bid - GU_EXP_BLOCKS;
    const int m0 = (sid >> 5) * 128;
    n0 = (sid & 31) * 64;
    mguard = 128;
#pragma unroll
    for (int i = 0; i < 2; ++i)
      asrc[i] = xb + (size_t)(m0 + i * 64 + arow) * CDIM + sc * 8;
    gbase = sgw_bk + n0;
    ubase = suw_bk + n0;
    hbase = h_sh + (size_t)m0 * SDIM + n0;
    hstride = SDIM;
  }

  // B staging: t<256 -> gate, t>=256 -> up. 2 x 16B per thread per K-step.
  // LDS layout per buf: el = np*1024 + k*16 + n  (np in 0..3, k in 0..63, n in 0..15)
  const int th = t & 255;
  bf16* bdst = (t >= 256) ? sBu : sBg;
  const bf16* Bp = (t >= 256) ? ubase : gbase;
  const bf16* bsrc[2];
#pragma unroll
  for (int i = 0; i < 2; ++i) {
    const int el2 = th * 8 + i * 2048;
    const int np = el2 >> 10;
    const int rem = el2 & 1023;
    const int kk = rem >> 4;
    const int n8 = (rem >> 3) & 1;
    bsrc[i] = Bp + (size_t)kk * (2 * HDIM) + np * 16 + n8 * 8;
  }
  const int adst = t * 8;
  const int bdoff = th * 8;

#define ISSUE_A(k_, ab_)                                                      \
  do {                                                                        \
    _Pragma("unroll")                                                         \
    for (int i = 0; i < 2; ++i)                                               \
      gload16(asrc[i] + (k_), &sA[(ab_) * 8192 + i * 4096 + adst]);           \
  } while (0)
#define ISSUE_B(k_, bo_)                                                      \
  do {                                                                        \
    _Pragma("unroll")                                                         \
    for (int i = 0; i < 2; ++i)                                               \
      gload16(bsrc[i] + (size_t)(k_) * (2 * HDIM),                            \
              &bdst[(bo_) + i * 2048 + bdoff]);                               \
  } while (0)

  const int wr = (wid >> 1) * 32, wc = (wid & 1) * 32;
  const int lrow = lane & 15, grp = lane >> 4;

  f32x4 ag[2][2], au[2][2];
#pragma unroll
  for (int m = 0; m < 2; ++m)
#pragma unroll
    for (int n = 0; n < 2; ++n)
#pragma unroll
      for (int i = 0; i < 4; ++i) { ag[m][n][i] = 0.f; au[m][n][i] = 0.f; }

#define COMPUTE(ab_, bo_)                                                     \
  do {                                                                        \
    _Pragma("unroll")                                                         \
    for (int ks = 0; ks < 2; ++ks) {                                          \
      u32x2 ra[2][2], rg[2][2], ru[2][2];                                     \
      _Pragma("unroll")                                                       \
      for (int m = 0; m < 2; ++m) {                                           \
        const int r = wr + m * 16 + lrow;                                     \
        _Pragma("unroll")                                                     \
        for (int h = 0; h < 2; ++h) {                                         \
          const int c = ks * 4 + h * 2 + (grp >> 1);                          \
          const u32 aaddr = (u32)(uintptr_t)&sA[(ab_) * 8192 + r * 64 +       \
                              ((c ^ (r & 7)) << 3) + (grp & 1) * 4];          \
          asm volatile("ds_read_b64 %0, %1" : "=v"(ra[m][h]) : "v"(aaddr));   \
        }                                                                     \
      }                                                                       \
      _Pragma("unroll")                                                       \
      for (int n = 0; n < 2; ++n) {                                           \
        const int np = (wid & 1) * 2 + n;                                     \
        _Pragma("unroll")                                                     \
        for (int h = 0; h < 2; ++h) {                                         \
          const int eb = (bo_) + np * 1024 + (ks * 32 + h * 16) * 16;         \
          const u32 ga = (u32)(uintptr_t)&sBg[eb] + lane * 8;                 \
          const u32 ua = (u32)(uintptr_t)&sBu[eb] + lane * 8;                 \
          asm volatile("ds_read_b64_tr_b16 %0, %1" : "=v"(rg[n][h]) : "v"(ga)); \
          asm volatile("ds_read_b64_tr_b16 %0, %1" : "=v"(ru[n][h]) : "v"(ua)); \
        }                                                                     \
      }                                                                       \
      WAIT_LGKM0();                                                           \
      FragU fa[2], fg[2], fu[2];                                              \
      _Pragma("unroll")                                                       \
      for (int m = 0; m < 2; ++m) {                                           \
        fa[m].w[0] = ra[m][0][0]; fa[m].w[1] = ra[m][0][1];                   \
        fa[m].w[2] = ra[m][1][0]; fa[m].w[3] = ra[m][1][1];                   \
      }                                                                       \
      _Pragma("unroll")                                                       \
      for (int n = 0; n < 2; ++n) {                                           \
        fg[n].w[0] = rg[n][0][0]; fg[n].w[1] = rg[n][0][1];                   \
        fg[n].w[2] = rg[n][1][0]; fg[n].w[3] = rg[n][1][1];                   \
        fu[n].w[0] = ru[n][0][0]; fu[n].w[1] = ru[n][0][1];                   \
        fu[n].w[2] = ru[n][1][0]; fu[n].w[3] = ru[n][1][1];                   \
      }                                                                       \
      _Pragma("unroll")                                                       \
      for (int m = 0; m < 2; ++m)                                             \
        _Pragma("unroll")                                                     \
        for (int n = 0; n < 2; ++n) {                                         \
          ag[m][n] = __builtin_amdgcn_mfma_f32_16x16x32_bf16(fa[m].v, fg[n].v, ag[m][n], 0, 0, 0); \
          au[m][n] = __builtin_amdgcn_mfma_f32_16x16x32_bf16(fa[m].v, fu[n].v, au[m][n], 0, 0, 0); \
        }                                                                     \
    }                                                                         \
  } while (0)

  ISSUE_A(0, 0);
  ISSUE_B(0, 0);
  SBAR0();
  ISSUE_B(64, 4096);
  SBAR0();
  WAIT_VM(2);
  __builtin_amdgcn_s_barrier();

  int bb0 = 0, bb1 = 4096, bb2 = 8192;
  for (int k = 0; k < 14; ++k) {       // 16 K-steps
    ISSUE_A((k + 1) * 64, (k + 1) & 1);
    SBAR0();
    ISSUE_B((k + 2) * 64, bb2);
    SBAR0();
    COMPUTE(k & 1, bb0);
    WAIT_VM(2);
    __builtin_amdgcn_s_barrier();
    int tmp = bb0; bb0 = bb1; bb1 = bb2; bb2 = tmp;
  }
  ISSUE_A(15 * 64, 1);
  SBAR0();
  COMPUTE(0, bb0);
  WAIT_VM(0);
  __builtin_amdgcn_s_barrier();
  { int tmp = bb0; bb0 = bb1; bb1 = bb2; bb2 = tmp; }
  COMPUTE(1, bb0);
#undef ISSUE_A
#undef ISSUE_B
#undef COMPUTE

  // SwiGLU epilogue (C/D: col=lane&15, row=grp*4+i — dtype/k-perm independent)
#pragma unroll
  for (int m = 0; m < 2; ++m) {
#pragma unroll
    for (int i = 0; i < 4; ++i) {
      const int rl = wr + m * 16 + grp * 4 + i;
      if (rl >= mguard) continue;
      bf16* orow = hbase + (size_t)rl * hstride;
#pragma unroll
      for (int n = 0; n < 2; ++n) {
        const float g = ag[m][n][i];
        const float u = au[m][n][i];
        orow[wc + n * 16 + lrow] = (bf16)(g * u * __builtin_amdgcn_rcpf(1.f + __expf(-g)));
      }
    }
  }
}

// ===== DOWN GEMM (8 waves, BK=64, counted vmcnt, tr-read B) ====================
__global__ __launch_bounds__(512, 2)
void dn10(const bf16* __restrict__ h_exp,
          const bf16* __restrict__ h_sh,
          const bf16* __restrict__ dw_bk,    // [E][1024k][1024n]
          const bf16* __restrict__ sdw_bk,   // [2048k][1024n]
          const float* __restrict__ entry_gate,
          bf16* __restrict__ out_e,
          float* __restrict__ out,
          const int* __restrict__ counts,
          const int* __restrict__ offsets,
          const int* __restrict__ tab128,
          const int* __restrict__ ntiles) {
  __shared__ __align__(16) bf16 sA[2 * 8192];   // 32 KB
  __shared__ __align__(16) bf16 sB[3 * 8192];   // 48 KB, [np 0..7][k][16n] per buf

  const int bid = xcd_swz(blockIdx.x, DN_NWG);
  const int t = threadIdx.x;
  const bool is_exp = bid < DN_EXP_BLOCKS;
  const int wid = t >> 6, lane = t & 63;

  int n0, mguard, K, rowbase, NK;
  const bf16* Ab;
  const bf16* Bb;

  if (is_exp) {
    const int slot = bid >> 3;
    if (slot >= ntiles[0]) return;
    const int packed = tab128[slot];
    const int e = packed >> 16;
    const int m0 = packed & 0xffff;
    const int cnt = counts[e];
    n0 = (bid & 7) * 128;
    mguard = cnt - m0;
    K = HDIM; NK = HDIM / 64;
    rowbase = offsets[e] + m0;
    Ab = h_exp;
    Bb = dw_bk + (size_t)e * HDIM * CDIM + n0;    // k-major, row stride 1024
  } else {
    const int sid = bid - DN_EXP_BLOCKS;
    const int m0 = (sid >> 3) * 128;
    n0 = (sid & 7) * 128;
    mguard = 128;
    K = SDIM; NK = SDIM / 64;
    rowbase = m0;
    Ab = h_sh;
    Bb = sdw_bk + n0;                              // k-major, row stride 1024
  }

  const int arow = t >> 3;
  const int sc = (t & 7) ^ (arow & 7);
  const bf16* asrc[2];
#pragma unroll
  for (int i = 0; i < 2; ++i) {
    int rg = rowbase + i * 64 + arow;
    if (is_exp && rg > N_TOK * TOPK - 1) rg = N_TOK * TOPK - 1;
    asrc[i] = Ab + (size_t)rg * K + sc * 8;
  }
  // B staging: 512 threads x 2 x 16B = 16KB/buf. el = np*1024 + k*16 + n.
  const bf16* bsrc[2];
#pragma unroll
  for (int i = 0; i < 2; ++i) {
    const int el2 = t * 8 + i * 4096;
    const int np = el2 >> 10;
    const int rem = el2 & 1023;
    const int kk = rem >> 4;
    const int n8 = (rem >> 3) & 1;
    bsrc[i] = Bb + (size_t)kk * CDIM + np * 16 + n8 * 8;
  }
  const int adst = t * 8;

#define ISSUE_A(k_, ab_)                                                      \
  do {                                                                        \
    _Pragma("unroll")                                                         \
    for (int i = 0; i < 2; ++i)                                               \
      gload16(asrc[i] + (k_), &sA[(ab_) * 8192 + i * 4096 + adst]);           \
  } while (0)
#define ISSUE_B(k_, bo_)                                                      \
  do {                                                                        \
    _Pragma("unroll")                                                         \
    for (int i = 0; i < 2; ++i)                                               \
      gload16(bsrc[i] + (size_t)(k_) * CDIM,                                  \
              &sB[(bo_) + i * 4096 + adst]);                                  \
  } while (0)

  const int wr = (wid >> 1) * 32, wc = (wid & 1) * 64;
  const int lrow = lane & 15, grp = lane >> 4;

  f32x4 acc[2][4];
#pragma unroll
  for (int m = 0; m < 2; ++m)
#pragma unroll
    for (int n = 0; n < 4; ++n)
#pragma unroll
      for (int i = 0; i < 4; ++i) acc[m][n][i] = 0.f;

#define COMPUTE(ab_, bo_)                                                     \
  do {                                                                        \
    _Pragma("unroll")                                                         \
    for (int ks = 0; ks < 2; ++ks) {                                          \
      u32x2 ra[2][2], rb[4][2];                                               \
      _Pragma("unroll")                                                       \
      for (int m = 0; m < 2; ++m) {                                           \
        const int r = wr + m * 16 + lrow;                                     \
        _Pragma("unroll")                                                     \
        for (int h = 0; h < 2; ++h) {                                         \
          const int c = ks * 4 + h * 2 + (grp >> 1);                          \
          const u32 aaddr = (u32)(uintptr_t)&sA[(ab_) * 8192 + r * 64 +       \
                              ((c ^ (r & 7)) << 3) + (grp & 1) * 4];          \
          asm volatile("ds_read_b64 %0, %1" : "=v"(ra[m][h]) : "v"(aaddr));   \
        }                                                                     \
      }                                                                       \
      _Pragma("unroll")                                                       \
      for (int n = 0; n < 4; ++n) {                                           \
        const int np = (wid & 1) * 4 + n;                                     \
        _Pragma("unroll")                                                     \
        for (int h = 0; h < 2; ++h) {                                         \
          const int eb = (bo_) + np * 1024 + (ks * 32 + h * 16) * 16;         \
          const u32 ba = (u32)(uintptr_t)&sB[eb] + lane * 8;                  \
          asm volatile("ds_read_b64_tr_b16 %0, %1" : "=v"(rb[n][h]) : "v"(ba)); \
        }                                                                     \
      }                                                                       \
      WAIT_LGKM0();                                                           \
      FragU fa[2], fb[4];                                                     \
      _Pragma("unroll")                                                       \
      for (int m = 0; m < 2; ++m) {                                           \
        fa[m].w[0] = ra[m][0][0]; fa[m].w[1] = ra[m][0][1];                   \
        fa[m].w[2] = ra[m][1][0]; fa[m].w[3] = ra[m][1][1];                   \
      }                                                                       \
      _Pragma("unroll")                                                       \
      for (int n = 0; n < 4; ++n) {                                           \
        fb[n].w[0] = rb[n][0][0]; fb[n].w[1] = rb[n][0][1];                   \
        fb[n].w[2] = rb[n][1][0]; fb[n].w[3] = rb[n][1][1];                   \
      }                                                                       \
      _Pragma("unroll")                                                       \
      for (int m = 0; m < 2; ++m)                                             \
        _Pragma("unroll")                                                     \
        for (int n = 0; n < 4; ++n)                                           \
          acc[m][n] = __builtin_amdgcn_mfma_f32_16x16x32_bf16(fa[m].v, fb[n].v, acc[m][n], 0, 0, 0); \
    }                                                                         \
  } while (0)

  ISSUE_A(0, 0);
  ISSUE_B(0, 0);
  SBAR0();
  ISSUE_B(64, 8192);
  SBAR0();
  WAIT_VM(2);
  __builtin_amdgcn_s_barrier();

  int bb0 = 0, bb1 = 8192, bb2 = 16384;
  for (int k = 0; k < NK - 2; ++k) {
    ISSUE_A((k + 1) * 64, (k + 1) & 1);
    SBAR0();
    ISSUE_B((k + 2) * 64, bb2);
    SBAR0();
    COMPUTE(k & 1, bb0);
    WAIT_VM(2);
    __builtin_amdgcn_s_barrier();
    int tmp = bb0; bb0 = bb1; bb1 = bb2; bb2 = tmp;
  }
  ISSUE_A((NK - 1) * 64, (NK - 1) & 1);
  SBAR0();
  COMPUTE((NK - 2) & 1, bb0);
  WAIT_VM(0);
  __builtin_amdgcn_s_barrier();
  { int tmp = bb0; bb0 = bb1; bb1 = bb2; bb2 = tmp; }
  COMPUTE((NK - 1) & 1, bb0);
#undef ISSUE_A
#undef ISSUE_B
#undef COMPUTE

#pragma unroll
  for (int m = 0; m < 2; ++m) {
#pragma unroll
    for (int i = 0; i < 4; ++i) {
      const int rl = wr + m * 16 + grp * 4 + i;
      if (rl >= mguard) continue;
      if (is_exp) {
        const int row = rowbase + rl;
        const float scl = entry_gate[row];
        bf16* orow = out_e + (size_t)row * CDIM + n0;
#pragma unroll
        for (int n = 0; n < 4; ++n)
          orow[wc + n * 16 + lrow] = (bf16)(acc[m][n][i] * scl);
      } else {
        float* orow = out + (size_t)(rowbase + rl) * CDIM + n0;
#pragma unroll
        for (int n = 0; n < 4; ++n)
          orow[wc + n * 16 + lrow] = acc[m][n][i];
      }
    }
  }
}

// ---------------- combine ----------------
__global__ void combine_kernel(float* __restrict__ out,
                               const bf16* __restrict__ out_e,
                               const int* __restrict__ entry_pos) {
  int tid = blockIdx.x * blockDim.x + threadIdx.x;
  int n = tid >> 8;
  int c4 = tid & 255;
  int p0 = entry_pos[2 * n];
  int p1 = entry_pos[2 * n + 1];
  float4 v = ((const float4*)out)[tid];
  ushort4 a = *(const ushort4*)((const u16*)out_e + (size_t)p0 * CDIM + c4 * 4);
  ushort4 b = *(const ushort4*)((const u16*)out_e + (size_t)p1 * CDIM + c4 * 4);
  v.x += fromb(a.x) + fromb(b.x);
  v.y += fromb(a.y) + fromb(b.y);
  v.z += fromb(a.z) + fromb(b.z);
  v.w += fromb(a.w) + fromb(b.w);
  ((float4*)out)[tid] = v;
}

extern "C" void kernel_launch(void* const* d_in, const int* in_sizes, int n_in,
                              void* d_out, int out_size, void* d_ws, size_t ws_size,
                              hipStream_t stream) {
  const float* x   = (const float*)d_in[0];
  const float* rw  = (const float*)d_in[1];
  const float* guw = (const float*)d_in[2];
  const float* dw  = (const float*)d_in[3];
  const float* sgw = (const float*)d_in[4];
  const float* suw = (const float*)d_in[5];
  const float* sdw = (const float*)d_in[6];
  float* out = (float*)d_out;
  char* ws = (char*)d_ws;
  const size_t MB = 1048576;

  int*   sel         = (int*)(ws + 0);
  float* gatew       = (float*)(ws + 16384);
  int*   counts      = (int*)(ws + 32768);
  int*   offsets     = (int*)(ws + 32832);
  int*   ntiles      = (int*)(ws + 32960);
  int*   tab128      = (int*)(ws + 33024);
  int*   entry_token = (int*)(ws + 33664);
  float* entry_gate  = (float*)(ws + 50048);
  int*   entry_pos   = (int*)(ws + 66432);

  bf16* xb     = (bf16*)(ws + 82816);                // 4 MB
  bf16* h_exp  = (bf16*)(ws + 82816 + 4 * MB);       // 8 MB
  bf16* h_sh   = (bf16*)(ws + 82816 + 12 * MB);      // 8 MB
  bf16* sgw_bk = (bf16*)(ws + 82816 + 20 * MB);      // 4 MB
  bf16* suw_bk = (bf16*)(ws + 82816 + 24 * MB);      // 4 MB
  bf16* guw_bk = (bf16*)(ws + 82816 + 28 * MB);      // 64 MB
  bf16* dw_bk  = (bf16*)(ws + 82816 + 92 * MB);      // 32 MB
  bf16* sdw_bk = (bf16*)(ws + 82816 + 124 * MB);     // 4 MB (peak ~128 MB)
  bf16* out_e  = sgw_bk;                             // 8 MB alias (dead after gu10)

  // 1) routing + fused x conversion
  router_kernel<<<N_TOK / 4, 256, 0, stream>>>(x, rw, xb, sel, gatew);

  // 2) guw flat convert + shared transposes + scan/scatter (one launch)
  prep_kernel<<<PREP_NWG, 256, 0, stream>>>(guw, sgw, suw, sdw,
                                            guw_bk, sgw_bk, suw_bk, sdw_bk,
                                            sel, gatew, counts, offsets, tab128,
                                            ntiles, entry_token, entry_gate, entry_pos);

  // 3) gate+up GEMM (tr-read B) + SwiGLU, with dw flat convert in trailing blocks
  gu10<<<GU9X_NWG, 512, 0, stream>>>(xb, guw_bk, sgw_bk, suw_bk, h_exp, h_sh,
                                     counts, offsets, entry_token, tab128, ntiles,
                                     dw, dw_bk);

  // 4) down GEMM (tr-read B)
  dn10<<<DN_NWG, 512, 0, stream>>>(h_exp, h_sh, dw_bk, sdw_bk, entry_gate, out_e, out,
                                   counts, offsets, tab128, ntiles);

  // 5) add gated expert contributions
  combine_kernel<<<(N_TOK * CDIM / 4) / 256, 256, 0, stream>>>(out, out_e, entry_pos);
}

// Round 17
// 168.986 us; speedup vs baseline: 1.0154x; 1.0154x over previous
//
#include <hip/hip_runtime.h>
#include <cstdint>

#define N_TOK 2048
#define CDIM  1024
#define NEXP  16
#define TOPK  2
#define HDIM  1024
#define SDIM  2048
#define ESLOT 48
#define GU_EXP_BLOCKS (ESLOT * 16)              // 768
#define GU_SH_BLOCKS  (16 * 32)                 // 512
#define GU_NWG (GU_EXP_BLOCKS + GU_SH_BLOCKS)   // 1280 (GEMM portion)
#define DW_CONV_BLOCKS 4096                     // flat dw convert, 4096 el/block
#define GU9X_NWG (GU_NWG + DW_CONV_BLOCKS)      // 5376
#define DN_EXP_BLOCKS (ESLOT * 8)               // 384
#define DN_SH_BLOCKS  (16 * 8)                  // 128
#define DN_NWG (DN_EXP_BLOCKS + DN_SH_BLOCKS)   // 512
#define PREP_GUW_BLKS 16384                     // 33.55M el / 2048
#define PREP_SH_BLKS  1536                      // 3 x 512 transpose tiles
#define PREP_NWG (1 + PREP_GUW_BLKS + PREP_SH_BLKS)

typedef __bf16 bf16;
typedef __bf16 bf16x8 __attribute__((ext_vector_type(8)));
typedef float  f32x4  __attribute__((ext_vector_type(4)));
typedef unsigned int u32;
typedef u32 u32x2 __attribute__((ext_vector_type(2)));
typedef unsigned short u16;

typedef __attribute__((address_space(3))) uint32_t lds_u32_t;
typedef __attribute__((address_space(1))) uint32_t glb_u32_t;

union FragU { u32 w[4]; bf16x8 v; };

__device__ __forceinline__ void gload16(const void* g, void* l) {
  __builtin_amdgcn_global_load_lds((const glb_u32_t*)(uintptr_t)g,
                                   (lds_u32_t*)(uintptr_t)l, 16, 0, 0);
}
__device__ __forceinline__ float fromb(u16 s) {
  union { float f; u32 u; } z; z.u = ((u32)s) << 16; return z.f;
}
__device__ __forceinline__ int xcd_swz(int bid, int nwg) {
  return (bid & 7) * (nwg >> 3) + (bid >> 3);
}
#define SBAR0() __builtin_amdgcn_sched_barrier(0)
#define WAIT_VM(N) do { asm volatile("s_waitcnt vmcnt(" #N ")" ::: "memory"); \
                        SBAR0(); } while (0)
#define WAIT_LGKM0() do { asm volatile("s_waitcnt lgkmcnt(0)" ::: "memory"); \
                          SBAR0(); } while (0)

// 64x64 transpose-convert tile: src [K][N] fp32 -> dst [N][K] bf16
__device__ __forceinline__ void conv_tile(const float* __restrict__ s,
                                          bf16* __restrict__ d,
                                          int K, int N, int k0, int n0,
                                          int t, float* ld) {
  const int kk = t >> 4, c4 = (t & 15) * 4;
#pragma unroll
  for (int q = 0; q < 4; ++q) {
    float4 f = *(const float4*)(s + (size_t)(k0 + kk + q * 16) * N + n0 + c4);
    float* lp = &ld[(kk + q * 16) * 68 + c4];
    lp[0] = f.x; lp[1] = f.y; lp[2] = f.z; lp[3] = f.w;
  }
  __syncthreads();
  const int nn = t >> 2, kc = (t & 3) * 16;
  bf16x8 v0, v1;
#pragma unroll
  for (int j = 0; j < 8; ++j) {
    v0[j] = (bf16)ld[(kc + j) * 68 + nn];
    v1[j] = (bf16)ld[(kc + 8 + j) * 68 + nn];
  }
  bf16* dp = d + (size_t)(n0 + nn) * K + k0 + kc;
  *(bf16x8*)dp = v0;
  *(bf16x8*)(dp + 8) = v1;
}

// ---------------- router (4 tokens/block, fused x->bf16) ----------------
__global__ __launch_bounds__(256)
void router_kernel(const float* __restrict__ x,
                   const float* __restrict__ rw,
                   bf16* __restrict__ xb,
                   int* __restrict__ sel,
                   float* __restrict__ gatew) {
  int n = blockIdx.x * 4 + (threadIdx.x >> 6);
  int lane = threadIdx.x & 63;
  const float* xr = x + (size_t)n * CDIM;
  float xv[16];
#pragma unroll
  for (int q = 0; q < 4; ++q) {
    float4 f = *(const float4*)(xr + lane * 16 + q * 4);
    xv[q * 4 + 0] = f.x; xv[q * 4 + 1] = f.y; xv[q * 4 + 2] = f.z; xv[q * 4 + 3] = f.w;
  }
  bf16x8 v0, v1;
#pragma unroll
  for (int j = 0; j < 8; ++j) { v0[j] = (bf16)xv[j]; v1[j] = (bf16)xv[8 + j]; }
  bf16* xo = xb + (size_t)n * CDIM + lane * 16;
  *(bf16x8*)xo = v0;
  *(bf16x8*)(xo + 8) = v1;
  float acc[NEXP];
#pragma unroll
  for (int e = 0; e < NEXP; ++e) {
    float a = 0.f;
    const float* rwe = rw + e * CDIM + lane * 16;
#pragma unroll
    for (int j = 0; j < 16; ++j) a += xv[j] * rwe[j];
    acc[e] = a;
  }
#pragma unroll
  for (int off = 32; off > 0; off >>= 1) {
#pragma unroll
    for (int e = 0; e < NEXP; ++e) acc[e] += __shfl_xor(acc[e], off, 64);
  }
  if (lane == 0) {
    int i0 = 0; float v0_ = acc[0];
#pragma unroll
    for (int e = 1; e < NEXP; ++e) if (acc[e] > v0_) { v0_ = acc[e]; i0 = e; }
    int i1 = (i0 == 0) ? 1 : 0; float v1_ = acc[i1];
#pragma unroll
    for (int e = 0; e < NEXP; ++e) if (e != i0 && acc[e] > v1_) { v1_ = acc[e]; i1 = e; }
    sel[2 * n] = i0; sel[2 * n + 1] = i1;
    gatew[2 * n]     = 1.f / (1.f + expf(-v0_));
    gatew[2 * n + 1] = 1.f / (1.f + expf(-v1_));
  }
}

// -------- prep: guw flat convert (streaming) + shared transposes + scan -------
__global__ __launch_bounds__(256)
void prep_kernel(const float* __restrict__ guw,
                 const float* __restrict__ sgw,
                 const float* __restrict__ suw,
                 const float* __restrict__ sdw,
                 bf16* __restrict__ guw_bk,    // [E][1024k][2048n] flat
                 bf16* __restrict__ sgw_bk,    // [1024c][2048s]
                 bf16* __restrict__ suw_bk,    // [1024c][2048s]
                 bf16* __restrict__ sdw_bk,    // [2048s][1024c]
                 const int* __restrict__ sel,
                 const float* __restrict__ gatew,
                 int* __restrict__ counts,
                 int* __restrict__ offsets,
                 int* __restrict__ tab128,
                 int* __restrict__ ntiles,
                 int* __restrict__ entry_token,
                 float* __restrict__ entry_gate,
                 int* __restrict__ entry_pos) {
  __shared__ __align__(16) float ld[64 * 68];
  const int b = blockIdx.x;
  const int t = threadIdx.x;
  if (b == 0) {
    int* hist = (int*)ld;
    int* cur = hist + NEXP;
    if (t < NEXP) hist[t] = 0;
    __syncthreads();
    for (int i = t; i < N_TOK * TOPK; i += 256) atomicAdd(&hist[sel[i]], 1);
    __syncthreads();
    if (t == 0) {
      int s = 0, a = 0;
      for (int e = 0; e < NEXP; ++e) {
        int c = hist[e];
        counts[e] = c; offsets[e] = s; cur[e] = s;
        for (int m0 = 0; m0 < c; m0 += 128) tab128[a++] = (e << 16) | m0;
        s += c;
      }
      ntiles[0] = a;
    }
    __syncthreads();
    for (int i = t; i < N_TOK * TOPK; i += 256) {
      int e = sel[i];
      int pos = atomicAdd(&cur[e], 1);
      entry_token[pos] = i >> 1;
      entry_gate[pos] = gatew[i];
      entry_pos[i] = pos;
    }
    return;
  }
  if (b <= PREP_GUW_BLKS) {
    // flat streaming convert of guw (layout preserved, k-major)
    size_t i = (size_t)(b - 1) * 2048 + t * 8;
    float4 f0 = *(const float4*)(guw + i);
    float4 f1 = *(const float4*)(guw + i + 4);
    bf16x8 v;
    v[0]=(bf16)f0.x; v[1]=(bf16)f0.y; v[2]=(bf16)f0.z; v[3]=(bf16)f0.w;
    v[4]=(bf16)f1.x; v[5]=(bf16)f1.y; v[6]=(bf16)f1.z; v[7]=(bf16)f1.w;
    *(bf16x8*)(guw_bk + i) = v;
    return;
  }
  // shared-weight transposes to k-major
  const int b2 = b - 1 - PREP_GUW_BLKS;   // 0..1535
  const int which = b2 >> 9;
  const int tile = b2 & 511;
  if (which == 0) {        // sgw [2048s][1024c] -> [1024c][2048s]
    conv_tile(sgw, sgw_bk, SDIM, CDIM, (tile >> 4) * 64, (tile & 15) * 64, t, ld);
  } else if (which == 1) { // suw
    conv_tile(suw, suw_bk, SDIM, CDIM, (tile >> 4) * 64, (tile & 15) * 64, t, ld);
  } else {                 // sdw [1024c][2048s] -> [2048s][1024c]
    conv_tile(sdw, sdw_bk, CDIM, SDIM, (tile >> 5) * 64, (tile & 31) * 64, t, ld);
  }
}

// ===== GU GEMM (8 waves, BK=64, counted vmcnt, tr-read B) + dw flat convert ====
// B panels are k-major bf16; LDS B layout [np][64k][16n] linear; fragments via
// ds_read_b64_tr_b16. A row-major as before; A frags via 2x ds_read_b64 with the
// matching k-permutation (grp*4 | 16+grp*4).
__global__ __launch_bounds__(512, 2)
void gu10(const bf16* __restrict__ xb,
          const bf16* __restrict__ guw_bk,   // [E][1024k][2048n]
          const bf16* __restrict__ sgw_bk,   // [1024k][2048n]
          const bf16* __restrict__ suw_bk,   // [1024k][2048n]
          bf16* __restrict__ h_exp,
          bf16* __restrict__ h_sh,
          const int* __restrict__ counts,
          const int* __restrict__ offsets,
          const int* __restrict__ entry_token,
          const int* __restrict__ tab128,
          const int* __restrict__ ntiles,
          const float* __restrict__ dw,
          bf16* __restrict__ dw_bk) {
  __shared__ __align__(16) bf16 sA[2 * 8192];    // 32 KB
  __shared__ __align__(16) bf16 sBg[3 * 4096];   // 24 KB, [np][k][16n] per buf
  __shared__ __align__(16) bf16 sBu[3 * 4096];   // 24 KB

  const int t = threadIdx.x;

  // trailing blocks: dw flat streaming convert
  if (blockIdx.x >= GU_NWG) {
    size_t i = (size_t)(blockIdx.x - GU_NWG) * 4096 + t * 8;
    float4 f0 = *(const float4*)(dw + i);
    float4 f1 = *(const float4*)(dw + i + 4);
    bf16x8 v;
    v[0]=(bf16)f0.x; v[1]=(bf16)f0.y; v[2]=(bf16)f0.z; v[3]=(bf16)f0.w;
    v[4]=(bf16)f1.x; v[5]=(bf16)f1.y; v[6]=(bf16)f1.z; v[7]=(bf16)f1.w;
    *(bf16x8*)(dw_bk + i) = v;
    return;
  }

  const int bid = xcd_swz(blockIdx.x, GU_NWG);
  const bool is_exp = bid < GU_EXP_BLOCKS;
  const int wid = t >> 6, lane = t & 63;

  int n0, mguard;
  bf16* hbase; int hstride;
  const bf16 *gbase, *ubase;   // k-major panel bases (row stride 2048)
  const int arow = t >> 3;
  const int sc = (t & 7) ^ (arow & 7);
  const bf16* asrc[2];

  if (is_exp) {
    const int slot = bid >> 4;
    if (slot >= ntiles[0]) return;
    const int packed = tab128[slot];
    const int e = packed >> 16;
    const int m0 = packed & 0xffff;
    const int cnt = counts[e];
    const int base = offsets[e];
    n0 = (bid & 15) * 64;
    mguard = cnt - m0;
#pragma unroll
    for (int i = 0; i < 2; ++i) {
      int r = m0 + i * 64 + arow;
      int tok = entry_token[base + ((r < cnt) ? r : (cnt - 1))];
      asrc[i] = xb + (size_t)tok * CDIM + sc * 8;
    }
    const bf16* we = guw_bk + (size_t)e * CDIM * (2 * HDIM);
    gbase = we + n0;
    ubase = we + HDIM + n0;
    hbase = h_exp + (size_t)(base + m0) * HDIM + n0;
    hstride = HDIM;
  } else {
    const int sid = bid - GU_EXP_BLOCKS;
    const int m0 = (sid >> 5) * 128;
    n0 = (sid & 31) * 64;
    mguard = 128;
#pragma unroll
    for (int i = 0; i < 2; ++i)
      asrc[i] = xb + (size_t)(m0 + i * 64 + arow) * CDIM + sc * 8;
    gbase = sgw_bk + n0;
    ubase = suw_bk + n0;
    hbase = h_sh + (size_t)m0 * SDIM + n0;
    hstride = SDIM;
  }

  // B staging: t<256 -> gate, t>=256 -> up. 2 x 16B per thread per K-step.
  // LDS layout per buf: el = np*1024 + k*16 + n  (np in 0..3, k in 0..63, n in 0..15)
  const int th = t & 255;
  bf16* bdst = (t >= 256) ? sBu : sBg;
  const bf16* Bp = (t >= 256) ? ubase : gbase;
  const bf16* bsrc[2];
#pragma unroll
  for (int i = 0; i < 2; ++i) {
    const int el2 = th * 8 + i * 2048;
    const int np = el2 >> 10;
    const int rem = el2 & 1023;
    const int kk = rem >> 4;
    const int n8 = (rem >> 3) & 1;
    bsrc[i] = Bp + (size_t)kk * (2 * HDIM) + np * 16 + n8 * 8;
  }
  const int adst = t * 8;
  const int bdoff = th * 8;

#define ISSUE_A(k_, ab_)                                                      \
  do {                                                                        \
    _Pragma("unroll")                                                         \
    for (int i = 0; i < 2; ++i)                                               \
      gload16(asrc[i] + (k_), &sA[(ab_) * 8192 + i * 4096 + adst]);           \
  } while (0)
#define ISSUE_B(k_, bo_)                                                      \
  do {                                                                        \
    _Pragma("unroll")                                                         \
    for (int i = 0; i < 2; ++i)                                               \
      gload16(bsrc[i] + (size_t)(k_) * (2 * HDIM),                            \
              &bdst[(bo_) + i * 2048 + bdoff]);                               \
  } while (0)

  const int wr = (wid >> 1) * 32, wc = (wid & 1) * 32;
  const int lrow = lane & 15, grp = lane >> 4;

  f32x4 ag[2][2], au[2][2];
#pragma unroll
  for (int m = 0; m < 2; ++m)
#pragma unroll
    for (int n = 0; n < 2; ++n)
#pragma unroll
      for (int i = 0; i < 4; ++i) { ag[m][n][i] = 0.f; au[m][n][i] = 0.f; }

#define COMPUTE(ab_, bo_)                                                     \
  do {                                                                        \
    _Pragma("unroll")                                                         \
    for (int ks = 0; ks < 2; ++ks) {                                          \
      u32x2 ra[2][2], rg[2][2], ru[2][2];                                     \
      _Pragma("unroll")                                                       \
      for (int m = 0; m < 2; ++m) {                                           \
        const int r = wr + m * 16 + lrow;                                     \
        _Pragma("unroll")                                                     \
        for (int h = 0; h < 2; ++h) {                                         \
          const int c = ks * 4 + h * 2 + (grp >> 1);                          \
          const u32 aaddr = (u32)(uintptr_t)&sA[(ab_) * 8192 + r * 64 +       \
                              ((c ^ (r & 7)) << 3) + (grp & 1) * 4];          \
          asm volatile("ds_read_b64 %0, %1" : "=v"(ra[m][h]) : "v"(aaddr));   \
        }                                                                     \
      }                                                                       \
      _Pragma("unroll")                                                       \
      for (int n = 0; n < 2; ++n) {                                           \
        const int np = (wid & 1) * 2 + n;                                     \
        _Pragma("unroll")                                                     \
        for (int h = 0; h < 2; ++h) {                                         \
          const int eb = (bo_) + np * 1024 + (ks * 32 + h * 16) * 16;         \
          const u32 ga = (u32)(uintptr_t)&sBg[eb] + lane * 8;                 \
          const u32 ua = (u32)(uintptr_t)&sBu[eb] + lane * 8;                 \
          asm volatile("ds_read_b64_tr_b16 %0, %1" : "=v"(rg[n][h]) : "v"(ga)); \
          asm volatile("ds_read_b64_tr_b16 %0, %1" : "=v"(ru[n][h]) : "v"(ua)); \
        }                                                                     \
      }                                                                       \
      WAIT_LGKM0();                                                           \
      FragU fa[2], fg[2], fu[2];                                              \
      _Pragma("unroll")                                                       \
      for (int m = 0; m < 2; ++m) {                                           \
        fa[m].w[0] = ra[m][0][0]; fa[m].w[1] = ra[m][0][1];                   \
        fa[m].w[2] = ra[m][1][0]; fa[m].w[3] = ra[m][1][1];                   \
      }                                                                       \
      _Pragma("unroll")                                                       \
      for (int n = 0; n < 2; ++n) {                                           \
        fg[n].w[0] = rg[n][0][0]; fg[n].w[1] = rg[n][0][1];                   \
        fg[n].w[2] = rg[n][1][0]; fg[n].w[3] = rg[n][1][1];                   \
        fu[n].w[0] = ru[n][0][0]; fu[n].w[1] = ru[n][0][1];                   \
        fu[n].w[2] = ru[n][1][0]; fu[n].w[3] = ru[n][1][1];                   \
      }                                                                       \
      _Pragma("unroll")                                                       \
      for (int m = 0; m < 2; ++m)                                             \
        _Pragma("unroll")                                                     \
        for (int n = 0; n < 2; ++n) {                                         \
          ag[m][n] = __builtin_amdgcn_mfma_f32_16x16x32_bf16(fa[m].v, fg[n].v, ag[m][n], 0, 0, 0); \
          au[m][n] = __builtin_amdgcn_mfma_f32_16x16x32_bf16(fa[m].v, fu[n].v, au[m][n], 0, 0, 0); \
        }                                                                     \
    }                                                                         \
  } while (0)

  ISSUE_A(0, 0);
  ISSUE_B(0, 0);
  SBAR0();
  ISSUE_B(64, 4096);
  SBAR0();
  WAIT_VM(2);
  __builtin_amdgcn_s_barrier();

  int bb0 = 0, bb1 = 4096, bb2 = 8192;
  for (int k = 0; k < 14; ++k) {       // 16 K-steps
    ISSUE_A((k + 1) * 64, (k + 1) & 1);
    SBAR0();
    ISSUE_B((k + 2) * 64, bb2);
    SBAR0();
    COMPUTE(k & 1, bb0);
    WAIT_VM(2);
    __builtin_amdgcn_s_barrier();
    int tmp = bb0; bb0 = bb1; bb1 = bb2; bb2 = tmp;
  }
  ISSUE_A(15 * 64, 1);
  SBAR0();
  COMPUTE(0, bb0);
  WAIT_VM(0);
  __builtin_amdgcn_s_barrier();
  { int tmp = bb0; bb0 = bb1; bb1 = bb2; bb2 = tmp; }
  COMPUTE(1, bb0);
#undef ISSUE_A
#undef ISSUE_B
#undef COMPUTE

  // SwiGLU epilogue (C/D: col=lane&15, row=grp*4+i — dtype/k-perm independent)
#pragma unroll
  for (int m = 0; m < 2; ++m) {
#pragma unroll
    for (int i = 0; i < 4; ++i) {
      const int rl = wr + m * 16 + grp * 4 + i;
      if (rl >= mguard) continue;
      bf16* orow = hbase + (size_t)rl * hstride;
#pragma unroll
      for (int n = 0; n < 2; ++n) {
        const float g = ag[m][n][i];
        const float u = au[m][n][i];
        orow[wc + n * 16 + lrow] = (bf16)(g * u * __builtin_amdgcn_rcpf(1.f + __expf(-g)));
      }
    }
  }
}

// ===== DOWN GEMM (8 waves, BK=64, counted vmcnt, tr-read B) ====================
__global__ __launch_bounds__(512, 2)
void dn10(const bf16* __restrict__ h_exp,
          const bf16* __restrict__ h_sh,
          const bf16* __restrict__ dw_bk,    // [E][1024k][1024n]
          const bf16* __restrict__ sdw_bk,   // [2048k][1024n]
          const float* __restrict__ entry_gate,
          bf16* __restrict__ out_e,
          float* __restrict__ out,
          const int* __restrict__ counts,
          const int* __restrict__ offsets,
          const int* __restrict__ tab128,
          const int* __restrict__ ntiles) {
  __shared__ __align__(16) bf16 sA[2 * 8192];   // 32 KB
  __shared__ __align__(16) bf16 sB[3 * 8192];   // 48 KB, [np 0..7][k][16n] per buf

  const int bid = xcd_swz(blockIdx.x, DN_NWG);
  const int t = threadIdx.x;
  const bool is_exp = bid < DN_EXP_BLOCKS;
  const int wid = t >> 6, lane = t & 63;

  int n0, mguard, K, rowbase, NK;
  const bf16* Ab;
  const bf16* Bb;

  if (is_exp) {
    const int slot = bid >> 3;
    if (slot >= ntiles[0]) return;
    const int packed = tab128[slot];
    const int e = packed >> 16;
    const int m0 = packed & 0xffff;
    const int cnt = counts[e];
    n0 = (bid & 7) * 128;
    mguard = cnt - m0;
    K = HDIM; NK = HDIM / 64;
    rowbase = offsets[e] + m0;
    Ab = h_exp;
    Bb = dw_bk + (size_t)e * HDIM * CDIM + n0;    // k-major, row stride 1024
  } else {
    const int sid = bid - DN_EXP_BLOCKS;
    const int m0 = (sid >> 3) * 128;
    n0 = (sid & 7) * 128;
    mguard = 128;
    K = SDIM; NK = SDIM / 64;
    rowbase = m0;
    Ab = h_sh;
    Bb = sdw_bk + n0;                              // k-major, row stride 1024
  }

  const int arow = t >> 3;
  const int sc = (t & 7) ^ (arow & 7);
  const bf16* asrc[2];
#pragma unroll
  for (int i = 0; i < 2; ++i) {
    int rg = rowbase + i * 64 + arow;
    if (is_exp && rg > N_TOK * TOPK - 1) rg = N_TOK * TOPK - 1;
    asrc[i] = Ab + (size_t)rg * K + sc * 8;
  }
  // B staging: 512 threads x 2 x 16B = 16KB/buf. el = np*1024 + k*16 + n.
  const bf16* bsrc[2];
#pragma unroll
  for (int i = 0; i < 2; ++i) {
    const int el2 = t * 8 + i * 4096;
    const int np = el2 >> 10;
    const int rem = el2 & 1023;
    const int kk = rem >> 4;
    const int n8 = (rem >> 3) & 1;
    bsrc[i] = Bb + (size_t)kk * CDIM + np * 16 + n8 * 8;
  }
  const int adst = t * 8;

#define ISSUE_A(k_, ab_)                                                      \
  do {                                                                        \
    _Pragma("unroll")                                                         \
    for (int i = 0; i < 2; ++i)                                               \
      gload16(asrc[i] + (k_), &sA[(ab_) * 8192 + i * 4096 + adst]);           \
  } while (0)
#define ISSUE_B(k_, bo_)                                                      \
  do {                                                                        \
    _Pragma("unroll")                                                         \
    for (int i = 0; i < 2; ++i)                                               \
      gload16(bsrc[i] + (size_t)(k_) * CDIM,                                  \
              &sB[(bo_) + i * 4096 + adst]);                                  \
  } while (0)

  const int wr = (wid >> 1) * 32, wc = (wid & 1) * 64;
  const int lrow = lane & 15, grp = lane >> 4;

  f32x4 acc[2][4];
#pragma unroll
  for (int m = 0; m < 2; ++m)
#pragma unroll
    for (int n = 0; n < 4; ++n)
#pragma unroll
      for (int i = 0; i < 4; ++i) acc[m][n][i] = 0.f;

#define COMPUTE(ab_, bo_)                                                     \
  do {                                                                        \
    _Pragma("unroll")                                                         \
    for (int ks = 0; ks < 2; ++ks) {                                          \
      u32x2 ra[2][2], rb[4][2];                                               \
      _Pragma("unroll")                                                       \
      for (int m = 0; m < 2; ++m) {                                           \
        const int r = wr + m * 16 + lrow;                                     \
        _Pragma("unroll")                                                     \
        for (int h = 0; h < 2; ++h) {                                         \
          const int c = ks * 4 + h * 2 + (grp >> 1);                          \
          const u32 aaddr = (u32)(uintptr_t)&sA[(ab_) * 8192 + r * 64 +       \
                              ((c ^ (r & 7)) << 3) + (grp & 1) * 4];          \
          asm volatile("ds_read_b64 %0, %1" : "=v"(ra[m][h]) : "v"(aaddr));   \
        }                                                                     \
      }                                                                       \
      _Pragma("unroll")                                                       \
      for (int n = 0; n < 4; ++n) {                                           \
        const int np = (wid & 1) * 4 + n;                                     \
        _Pragma("unroll")                                                     \
        for (int h = 0; h < 2; ++h) {                                         \
          const int eb = (bo_) + np * 1024 + (ks * 32 + h * 16) * 16;         \
          const u32 ba = (u32)(uintptr_t)&sB[eb] + lane * 8;                  \
          asm volatile("ds_read_b64_tr_b16 %0, %1" : "=v"(rb[n][h]) : "v"(ba)); \
        }                                                                     \
      }                                                                       \
      WAIT_LGKM0();                                                           \
      FragU fa[2], fb[4];                                                     \
      _Pragma("unroll")                                                       \
      for (int m = 0; m < 2; ++m) {                                           \
        fa[m].w[0] = ra[m][0][0]; fa[m].w[1] = ra[m][0][1];                   \
        fa[m].w[2] = ra[m][1][0]; fa[m].w[3] = ra[m][1][1];                   \
      }                                                                       \
      _Pragma("unroll")                                                       \
      for (int n = 0; n < 4; ++n) {                                           \
        fb[n].w[0] = rb[n][0][0]; fb[n].w[1] = rb[n][0][1];                   \
        fb[n].w[2] = rb[n][1][0]; fb[n].w[3] = rb[n][1][1];                   \
      }                                                                       \
      _Pragma("unroll")                                                       \
      for (int m = 0; m < 2; ++m)                                             \
        _Pragma("unroll")                                                     \
        for (int n = 0; n < 4; ++n)                                           \
          acc[m][n] = __builtin_amdgcn_mfma_f32_16x16x32_bf16(fa[m].v, fb[n].v, acc[m][n], 0, 0, 0); \
    }                                                                         \
  } while (0)

  ISSUE_A(0, 0);
  ISSUE_B(0, 0);
  SBAR0();
  ISSUE_B(64, 8192);
  SBAR0();
  WAIT_VM(2);
  __builtin_amdgcn_s_barrier();

  int bb0 = 0, bb1 = 8192, bb2 = 16384;
  for (int k = 0; k < NK - 2; ++k) {
    ISSUE_A((k + 1) * 64, (k + 1) & 1);
    SBAR0();
    ISSUE_B((k + 2) * 64, bb2);
    SBAR0();
    COMPUTE(k & 1, bb0);
    WAIT_VM(2);
    __builtin_amdgcn_s_barrier();
    int tmp = bb0; bb0 = bb1; bb1 = bb2; bb2 = tmp;
  }
  ISSUE_A((NK - 1) * 64, (NK - 1) & 1);
  SBAR0();
  COMPUTE((NK - 2) & 1, bb0);
  WAIT_VM(0);
  __builtin_amdgcn_s_barrier();
  { int tmp = bb0; bb0 = bb1; bb1 = bb2; bb2 = tmp; }
  COMPUTE((NK - 1) & 1, bb0);
#undef ISSUE_A
#undef ISSUE_B
#undef COMPUTE

#pragma unroll
  for (int m = 0; m < 2; ++m) {
#pragma unroll
    for (int i = 0; i < 4; ++i) {
      const int rl = wr + m * 16 + grp * 4 + i;
      if (rl >= mguard) continue;
      if (is_exp) {
        const int row = rowbase + rl;
        const float scl = entry_gate[row];
        bf16* orow = out_e + (size_t)row * CDIM + n0;
#pragma unroll
        for (int n = 0; n < 4; ++n)
          orow[wc + n * 16 + lrow] = (bf16)(acc[m][n][i] * scl);
      } else {
        float* orow = out + (size_t)(rowbase + rl) * CDIM + n0;
#pragma unroll
        for (int n = 0; n < 4; ++n)
          orow[wc + n * 16 + lrow] = acc[m][n][i];
      }
    }
  }
}

// ---------------- combine ----------------
__global__ void combine_kernel(float* __restrict__ out,
                               const bf16* __restrict__ out_e,
                               const int* __restrict__ entry_pos) {
  int tid = blockIdx.x * blockDim.x + threadIdx.x;
  int n = tid >> 8;
  int c4 = tid & 255;
  int p0 = entry_pos[2 * n];
  int p1 = entry_pos[2 * n + 1];
  float4 v = ((const float4*)out)[tid];
  ushort4 a = *(const ushort4*)((const u16*)out_e + (size_t)p0 * CDIM + c4 * 4);
  ushort4 b = *(const ushort4*)((const u16*)out_e + (size_t)p1 * CDIM + c4 * 4);
  v.x += fromb(a.x) + fromb(b.x);
  v.y += fromb(a.y) + fromb(b.y);
  v.z += fromb(a.z) + fromb(b.z);
  v.w += fromb(a.w) + fromb(b.w);
  ((float4*)out)[tid] = v;
}

extern "C" void kernel_launch(void* const* d_in, const int* in_sizes, int n_in,
                              void* d_out, int out_size, void* d_ws, size_t ws_size,
                              hipStream_t stream) {
  const float* x   = (const float*)d_in[0];
  const float* rw  = (const float*)d_in[1];
  const float* guw = (const float*)d_in[2];
  const float* dw  = (const float*)d_in[3];
  const float* sgw = (const float*)d_in[4];
  const float* suw = (const float*)d_in[5];
  const float* sdw = (const float*)d_in[6];
  float* out = (float*)d_out;
  char* ws = (char*)d_ws;
  const size_t MB = 1048576;

  int*   sel         = (int*)(ws + 0);
  float* gatew       = (float*)(ws + 16384);
  int*   counts      = (int*)(ws + 32768);
  int*   offsets     = (int*)(ws + 32832);
  int*   ntiles      = (int*)(ws + 32960);
  int*   tab128      = (int*)(ws + 33024);
  int*   entry_token = (int*)(ws + 33664);
  float* entry_gate  = (float*)(ws + 50048);
  int*   entry_pos   = (int*)(ws + 66432);

  bf16* xb     = (bf16*)(ws + 82816);                // 4 MB
  bf16* h_exp  = (bf16*)(ws + 82816 + 4 * MB);       // 8 MB
  bf16* h_sh   = (bf16*)(ws + 82816 + 12 * MB);      // 8 MB
  bf16* sgw_bk = (bf16*)(ws + 82816 + 20 * MB);      // 4 MB
  bf16* suw_bk = (bf16*)(ws + 82816 + 24 * MB);      // 4 MB
  bf16* guw_bk = (bf16*)(ws + 82816 + 28 * MB);      // 64 MB
  bf16* dw_bk  = (bf16*)(ws + 82816 + 92 * MB);      // 32 MB
  bf16* sdw_bk = (bf16*)(ws + 82816 + 124 * MB);     // 4 MB (peak ~128 MB)
  bf16* out_e  = sgw_bk;                             // 8 MB alias (dead after gu10)

  // 1) routing + fused x conversion
  router_kernel<<<N_TOK / 4, 256, 0, stream>>>(x, rw, xb, sel, gatew);

  // 2) guw flat convert + shared transposes + scan/scatter (one launch)
  prep_kernel<<<PREP_NWG, 256, 0, stream>>>(guw, sgw, suw, sdw,
                                            guw_bk, sgw_bk, suw_bk, sdw_bk,
                                            sel, gatew, counts, offsets, tab128,
                                            ntiles, entry_token, entry_gate, entry_pos);

  // 3) gate+up GEMM (tr-read B) + SwiGLU, with dw flat convert in trailing blocks
  gu10<<<GU9X_NWG, 512, 0, stream>>>(xb, guw_bk, sgw_bk, suw_bk, h_exp, h_sh,
                                     counts, offsets, entry_token, tab128, ntiles,
                                     dw, dw_bk);

  // 4) down GEMM (tr-read B)
  dn10<<<DN_NWG, 512, 0, stream>>>(h_exp, h_sh, dw_bk, sdw_bk, entry_gate, out_e, out,
                                   counts, offsets, tab128, ntiles);

  // 5) add gated expert contributions
  combine_kernel<<<(N_TOK * CDIM / 4) / 256, 256, 0, stream>>>(out, out_e, entry_pos);
}

// Round 18
// 157.877 us; speedup vs baseline: 1.0868x; 1.0704x over previous
//
#include <hip/hip_runtime.h>
#include <cstdint>

#define N_TOK 2048
#define CDIM  1024
#define NEXP  16
#define TOPK  2
#define HDIM  1024
#define SDIM  2048
#define ESLOT 48
#define GU_EXP_BLOCKS (ESLOT * 16)              // 768
#define GU_SH_BLOCKS  (16 * 32)                 // 512
#define GU_NWG (GU_EXP_BLOCKS + GU_SH_BLOCKS)   // 1280 (GEMM portion)
#define DW_CONV_BLOCKS 2048                     // 4096 dw tiles, 2/block
#define GU9X_NWG (GU_NWG + DW_CONV_BLOCKS)      // 3328
#define DN_EXP_BLOCKS (ESLOT * 8)               // 384
#define DN_SH_BLOCKS  (16 * 8)                  // 128
#define DN_NWG (DN_EXP_BLOCKS + DN_SH_BLOCKS)   // 512
#define PREP_GUW_TILES 8192                     // 32n x 16k x 16e
#define PREP_NWG (1 + PREP_GUW_TILES + 3072)    // 11265

typedef __bf16 bf16;
typedef __bf16 bf16x8 __attribute__((ext_vector_type(8)));
typedef float  f32x4  __attribute__((ext_vector_type(4)));
typedef unsigned int u32;
typedef unsigned short u16;

typedef __attribute__((address_space(3))) uint32_t lds_u32_t;
typedef __attribute__((address_space(1))) uint32_t glb_u32_t;

__device__ __forceinline__ void gload16(const void* g, void* l) {
  __builtin_amdgcn_global_load_lds((const glb_u32_t*)(uintptr_t)g,
                                   (lds_u32_t*)(uintptr_t)l, 16, 0, 0);
}
__device__ __forceinline__ float fromb(u16 s) {
  union { float f; u32 u; } z; z.u = ((u32)s) << 16; return z.f;
}
__device__ __forceinline__ int xcd_swz(int bid, int nwg) {
  return (bid & 7) * (nwg >> 3) + (bid >> 3);
}
#define SBAR0() __builtin_amdgcn_sched_barrier(0)
#define WAIT_VM(N) do { asm volatile("s_waitcnt vmcnt(" #N ")" ::: "memory"); \
                        SBAR0(); } while (0)

// transpose-convert one 64x64 tile: src [K][N] fp32 -> dst [N][K] bf16
__device__ __forceinline__ void conv_tile(const float* __restrict__ s,
                                          bf16* __restrict__ d,
                                          int K, int N, int k0, int n0,
                                          int t, float* ld) {
  const int kk = t >> 4, c4 = (t & 15) * 4;
#pragma unroll
  for (int q = 0; q < 4; ++q) {
    float4 f = *(const float4*)(s + (size_t)(k0 + kk + q * 16) * N + n0 + c4);
    float* lp = &ld[(kk + q * 16) * 68 + c4];
    lp[0] = f.x; lp[1] = f.y; lp[2] = f.z; lp[3] = f.w;
  }
  __syncthreads();
  const int nn = t >> 2, kc = (t & 3) * 16;
  bf16x8 v0, v1;
#pragma unroll
  for (int j = 0; j < 8; ++j) {
    v0[j] = (bf16)ld[(kc + j) * 68 + nn];
    v1[j] = (bf16)ld[(kc + 8 + j) * 68 + nn];
  }
  bf16* dp = d + (size_t)(n0 + nn) * K + k0 + kc;
  *(bf16x8*)dp = v0;
  *(bf16x8*)(dp + 8) = v1;
}

// ---------------- router (4 tokens/block, fused x->bf16) ----------------
__global__ __launch_bounds__(256)
void router_kernel(const float* __restrict__ x,
                   const float* __restrict__ rw,
                   bf16* __restrict__ xb,
                   int* __restrict__ sel,
                   float* __restrict__ gatew) {
  int n = blockIdx.x * 4 + (threadIdx.x >> 6);
  int lane = threadIdx.x & 63;
  const float* xr = x + (size_t)n * CDIM;
  float xv[16];
#pragma unroll
  for (int q = 0; q < 4; ++q) {
    float4 f = *(const float4*)(xr + lane * 16 + q * 4);
    xv[q * 4 + 0] = f.x; xv[q * 4 + 1] = f.y; xv[q * 4 + 2] = f.z; xv[q * 4 + 3] = f.w;
  }
  bf16x8 v0, v1;
#pragma unroll
  for (int j = 0; j < 8; ++j) { v0[j] = (bf16)xv[j]; v1[j] = (bf16)xv[8 + j]; }
  bf16* xo = xb + (size_t)n * CDIM + lane * 16;
  *(bf16x8*)xo = v0;
  *(bf16x8*)(xo + 8) = v1;
  float acc[NEXP];
#pragma unroll
  for (int e = 0; e < NEXP; ++e) {
    float a = 0.f;
    const float* rwe = rw + e * CDIM + lane * 16;
#pragma unroll
    for (int j = 0; j < 16; ++j) a += xv[j] * rwe[j];
    acc[e] = a;
  }
#pragma unroll
  for (int off = 32; off > 0; off >>= 1) {
#pragma unroll
    for (int e = 0; e < NEXP; ++e) acc[e] += __shfl_xor(acc[e], off, 64);
  }
  if (lane == 0) {
    int i0 = 0; float v0_ = acc[0];
#pragma unroll
    for (int e = 1; e < NEXP; ++e) if (acc[e] > v0_) { v0_ = acc[e]; i0 = e; }
    int i1 = (i0 == 0) ? 1 : 0; float v1_ = acc[i1];
#pragma unroll
    for (int e = 0; e < NEXP; ++e) if (e != i0 && acc[e] > v1_) { v1_ = acc[e]; i1 = e; }
    sel[2 * n] = i0; sel[2 * n + 1] = i1;
    gatew[2 * n]     = 1.f / (1.f + expf(-v0_));
    gatew[2 * n + 1] = 1.f / (1.f + expf(-v1_));
  }
}

// ---------------- prep: guw transpose-convert + small converts + scan ---------
__global__ __launch_bounds__(256)
void prep_kernel(const float* __restrict__ guw,
                 const float* __restrict__ sgw,
                 const float* __restrict__ suw,
                 const float* __restrict__ sdw,
                 bf16* __restrict__ guw_b,
                 bf16* __restrict__ sgw_b,
                 bf16* __restrict__ suw_b,
                 bf16* __restrict__ sdw_b,
                 const int* __restrict__ sel,
                 const float* __restrict__ gatew,
                 int* __restrict__ counts,
                 int* __restrict__ offsets,
                 int* __restrict__ tab128,
                 int* __restrict__ ntiles,
                 int* __restrict__ entry_token,
                 float* __restrict__ entry_gate,
                 int* __restrict__ entry_pos) {
  __shared__ __align__(16) float ld[64 * 68];
  const int b = blockIdx.x;
  const int t = threadIdx.x;
  if (b == 0) {
    int* hist = (int*)ld;
    int* cur = hist + NEXP;
    if (t < NEXP) hist[t] = 0;
    __syncthreads();
    for (int i = t; i < N_TOK * TOPK; i += 256) atomicAdd(&hist[sel[i]], 1);
    __syncthreads();
    if (t == 0) {
      int s = 0, a = 0;
      for (int e = 0; e < NEXP; ++e) {
        int c = hist[e];
        counts[e] = c; offsets[e] = s; cur[e] = s;
        for (int m0 = 0; m0 < c; m0 += 128) tab128[a++] = (e << 16) | m0;
        s += c;
      }
      ntiles[0] = a;
    }
    __syncthreads();
    for (int i = t; i < N_TOK * TOPK; i += 256) {
      int e = sel[i];
      int pos = atomicAdd(&cur[e], 1);
      entry_token[pos] = i >> 1;
      entry_gate[pos] = gatew[i];
      entry_pos[i] = pos;
    }
    return;
  }
  if (b <= PREP_GUW_TILES) {
    const int idx = b - 1;
    const int e = idx >> 9;           // 512 tiles/expert (32n x 16k)
    const int rem = idx & 511;
    const int n0 = (rem & 31) << 6;
    const int k0 = (rem >> 5) << 6;
    conv_tile(guw + (size_t)e * CDIM * 2 * HDIM,
              guw_b + (size_t)e * 2 * HDIM * CDIM,
              CDIM, 2 * HDIM, k0, n0, t, ld);
    return;
  }
  const int b2 = b - 1 - PREP_GUW_TILES;   // 0..3071
  const float* s; bf16* d;
  if (b2 < 1024)      { s = sgw; d = sgw_b; }
  else if (b2 < 2048) { s = suw; d = suw_b; }
  else                { s = sdw; d = sdw_b; }
  int i = ((b2 & 1023) * 256 + t) * 8;
  float4 f0 = *(const float4*)(s + i);
  float4 f1 = *(const float4*)(s + i + 4);
  bf16x8 v;
  v[0]=(bf16)f0.x; v[1]=(bf16)f0.y; v[2]=(bf16)f0.z; v[3]=(bf16)f0.w;
  v[4]=(bf16)f1.x; v[5]=(bf16)f1.y; v[6]=(bf16)f1.z; v[7]=(bf16)f1.w;
  *(bf16x8*)(d + i) = v;
}

// ================= GU GEMM (8 waves, BK=64, counted vmcnt) + dw convert =======
__global__ __launch_bounds__(512, 2)
void gu9x(const bf16* __restrict__ xb,
          const bf16* __restrict__ guwb,
          const bf16* __restrict__ sgwb,
          const bf16* __restrict__ suwb,
          bf16* __restrict__ h_exp,
          bf16* __restrict__ h_sh,
          const int* __restrict__ counts,
          const int* __restrict__ offsets,
          const int* __restrict__ entry_token,
          const int* __restrict__ tab128,
          const int* __restrict__ ntiles,
          const float* __restrict__ dw,
          bf16* __restrict__ dw_b) {
  __shared__ __align__(16) char smem[81920];
  bf16* sA  = (bf16*)smem;             // 2 x 128x64 = 32 KB
  bf16* sBg = (bf16*)(smem + 32768);   // 3 x 64x64  = 24 KB
  bf16* sBu = (bf16*)(smem + 57344);   // 24 KB

  const int t = threadIdx.x;

  // trailing blocks: dw transpose-convert, 2 tiles per block (one per 256-half)
  if (blockIdx.x >= GU_NWG) {
    const int tid2 = (blockIdx.x - GU_NWG) * 2 + (t >> 8);
    float* ld = (float*)(smem + (t >> 8) * 17408);
    const int e = tid2 >> 8;           // 256 tiles/expert (16n x 16k)
    const int rem = tid2 & 255;
    const int n0c = (rem & 15) << 6;
    const int k0c = (rem >> 4) << 6;
    conv_tile(dw + (size_t)e * HDIM * CDIM,
              dw_b + (size_t)e * CDIM * HDIM,
              HDIM, CDIM, k0c, n0c, t & 255, ld);
    return;
  }

  const int bid = xcd_swz(blockIdx.x, GU_NWG);
  const bool is_exp = bid < GU_EXP_BLOCKS;
  const int wid = t >> 6, lane = t & 63;

  int n0, mguard;
  bf16* hbase; int hstride;
  const bf16 *Bg, *Bu;
  const int arow = t >> 3;
  const int sc = (t & 7) ^ (arow & 7);
  const bf16* asrc[2];

  if (is_exp) {
    const int slot = bid >> 4;
    if (slot >= ntiles[0]) return;
    const int packed = tab128[slot];
    const int e = packed >> 16;
    const int m0 = packed & 0xffff;
    const int cnt = counts[e];
    const int base = offsets[e];
    n0 = (bid & 15) * 64;
    mguard = cnt - m0;
#pragma unroll
    for (int i = 0; i < 2; ++i) {
      int r = m0 + i * 64 + arow;
      int tok = entry_token[base + ((r < cnt) ? r : (cnt - 1))];
      asrc[i] = xb + (size_t)tok * CDIM + sc * 8;
    }
    const bf16* we = guwb + (size_t)e * (2 * HDIM) * CDIM;
    Bg = we + (size_t)n0 * CDIM;
    Bu = we + (size_t)(HDIM + n0) * CDIM;
    hbase = h_exp + (size_t)(base + m0) * HDIM + n0;
    hstride = HDIM;
  } else {
    const int sid = bid - GU_EXP_BLOCKS;
    const int m0 = (sid >> 5) * 128;
    n0 = (sid & 31) * 64;
    mguard = 128;
#pragma unroll
    for (int i = 0; i < 2; ++i)
      asrc[i] = xb + (size_t)(m0 + i * 64 + arow) * CDIM + sc * 8;
    Bg = sgwb + (size_t)n0 * CDIM;
    Bu = suwb + (size_t)n0 * CDIM;
    hbase = h_sh + (size_t)m0 * SDIM + n0;
    hstride = SDIM;
  }

  const int th = t & 255;
  bf16* bdst = (t >= 256) ? sBu : sBg;
  const bf16* Bp = (t >= 256) ? Bu : Bg;
  const bf16* bsrc[2];
#pragma unroll
  for (int i = 0; i < 2; ++i) {
    const int row = i * 32 + (th >> 3);
    const int c = (th & 7) ^ (row & 7);
    bsrc[i] = Bp + (size_t)row * CDIM + c * 8;
  }
  const int adst = t * 8;
  const int bdoff = th * 8;

#define ISSUE_A(k_, ab_)                                                      \
  do {                                                                        \
    _Pragma("unroll")                                                         \
    for (int i = 0; i < 2; ++i)                                               \
      gload16(asrc[i] + (k_), &sA[(ab_) * 8192 + i * 4096 + adst]);           \
  } while (0)
#define ISSUE_B(k_, bo_)                                                      \
  do {                                                                        \
    _Pragma("unroll")                                                         \
    for (int i = 0; i < 2; ++i)                                               \
      gload16(bsrc[i] + (k_), &bdst[(bo_) + i * 2048 + bdoff]);               \
  } while (0)

  const int wr = (wid >> 1) * 32, wc = (wid & 1) * 32;
  const int lrow = lane & 15, grp = lane >> 4;

  f32x4 ag[2][2], au[2][2];
#pragma unroll
  for (int m = 0; m < 2; ++m)
#pragma unroll
    for (int n = 0; n < 2; ++n)
#pragma unroll
      for (int i = 0; i < 4; ++i) { ag[m][n][i] = 0.f; au[m][n][i] = 0.f; }

#define COMPUTE(ab_, bo_)                                                     \
  do {                                                                        \
    _Pragma("unroll")                                                         \
    for (int ks = 0; ks < 2; ++ks) {                                          \
      const int ch = ks * 4 + grp;                                            \
      bf16x8 av[2], bg[2], bu[2];                                             \
      _Pragma("unroll")                                                       \
      for (int m = 0; m < 2; ++m) {                                           \
        const int r = wr + m * 16 + lrow;                                     \
        av[m] = *(const bf16x8*)&sA[(ab_) * 8192 + r * 64 + ((ch ^ (r & 7)) << 3)]; \
      }                                                                       \
      _Pragma("unroll")                                                       \
      for (int n = 0; n < 2; ++n) {                                           \
        const int r = wc + n * 16 + lrow;                                     \
        const int so = r * 64 + ((ch ^ (r & 7)) << 3);                        \
        bg[n] = *(const bf16x8*)&sBg[(bo_) + so];                             \
        bu[n] = *(const bf16x8*)&sBu[(bo_) + so];                             \
      }                                                                       \
      _Pragma("unroll")                                                       \
      for (int m = 0; m < 2; ++m)                                             \
        _Pragma("unroll")                                                     \
        for (int n = 0; n < 2; ++n) {                                         \
          ag[m][n] = __builtin_amdgcn_mfma_f32_16x16x32_bf16(av[m], bg[n], ag[m][n], 0, 0, 0); \
          au[m][n] = __builtin_amdgcn_mfma_f32_16x16x32_bf16(av[m], bu[n], au[m][n], 0, 0, 0); \
        }                                                                     \
    }                                                                         \
  } while (0)

  ISSUE_A(0, 0);
  ISSUE_B(0, 0);
  SBAR0();
  ISSUE_B(64, 4096);
  SBAR0();
  WAIT_VM(2);
  __builtin_amdgcn_s_barrier();

  int bb0 = 0, bb1 = 4096, bb2 = 8192;
  for (int k = 0; k < 14; ++k) {
    ISSUE_A((k + 1) * 64, (k + 1) & 1);
    SBAR0();
    ISSUE_B((k + 2) * 64, bb2);
    SBAR0();
    COMPUTE(k & 1, bb0);
    WAIT_VM(2);
    __builtin_amdgcn_s_barrier();
    int tmp = bb0; bb0 = bb1; bb1 = bb2; bb2 = tmp;
  }
  ISSUE_A(15 * 64, 1);
  SBAR0();
  COMPUTE(0, bb0);
  WAIT_VM(0);
  __builtin_amdgcn_s_barrier();
  { int tmp = bb0; bb0 = bb1; bb1 = bb2; bb2 = tmp; }
  COMPUTE(1, bb0);
#undef ISSUE_A
#undef ISSUE_B
#undef COMPUTE

#pragma unroll
  for (int m = 0; m < 2; ++m) {
#pragma unroll
    for (int i = 0; i < 4; ++i) {
      const int rl = wr + m * 16 + grp * 4 + i;
      if (rl >= mguard) continue;
      bf16* orow = hbase + (size_t)rl * hstride;
#pragma unroll
      for (int n = 0; n < 2; ++n) {
        const float g = ag[m][n][i];
        const float u = au[m][n][i];
        orow[wc + n * 16 + lrow] = (bf16)(g * u * __builtin_amdgcn_rcpf(1.f + __expf(-g)));
      }
    }
  }
}

// ================= DOWN GEMM (8 waves, BK=64, counted vmcnt) ==================
__global__ __launch_bounds__(512, 2)
void dn9(const bf16* __restrict__ h_exp,
         const bf16* __restrict__ h_sh,
         const bf16* __restrict__ dwb,
         const bf16* __restrict__ sdwb,
         const float* __restrict__ entry_gate,
         bf16* __restrict__ out_e,
         float* __restrict__ out,
         const int* __restrict__ counts,
         const int* __restrict__ offsets,
         const int* __restrict__ tab128,
         const int* __restrict__ ntiles) {
  __shared__ __align__(16) bf16 sA[2 * 8192];
  __shared__ __align__(16) bf16 sB[3 * 8192];

  const int bid = xcd_swz(blockIdx.x, DN_NWG);
  const int t = threadIdx.x;
  const bool is_exp = bid < DN_EXP_BLOCKS;
  const int wid = t >> 6, lane = t & 63;

  int n0, mguard, K, rowbase, NK;
  const bf16* Ab;
  const bf16* Bb;

  if (is_exp) {
    const int slot = bid >> 3;
    if (slot >= ntiles[0]) return;
    const int packed = tab128[slot];
    const int e = packed >> 16;
    const int m0 = packed & 0xffff;
    const int cnt = counts[e];
    n0 = (bid & 7) * 128;
    mguard = cnt - m0;
    K = HDIM; NK = HDIM / 64;
    rowbase = offsets[e] + m0;
    Ab = h_exp;
    Bb = dwb + (size_t)e * CDIM * HDIM + (size_t)n0 * HDIM;
  } else {
    const int sid = bid - DN_EXP_BLOCKS;
    const int m0 = (sid >> 3) * 128;
    n0 = (sid & 7) * 128;
    mguard = 128;
    K = SDIM; NK = SDIM / 64;
    rowbase = m0;
    Ab = h_sh;
    Bb = sdwb + (size_t)n0 * SDIM;
  }

  const int arow = t >> 3;
  const int sc = (t & 7) ^ (arow & 7);
  const bf16* asrc[2];
#pragma unroll
  for (int i = 0; i < 2; ++i) {
    int rg = rowbase + i * 64 + arow;
    if (is_exp && rg > N_TOK * TOPK - 1) rg = N_TOK * TOPK - 1;
    asrc[i] = Ab + (size_t)rg * K + sc * 8;
  }
  const bf16* bsrc[2];
#pragma unroll
  for (int i = 0; i < 2; ++i)
    bsrc[i] = Bb + (size_t)(i * 64 + arow) * K + sc * 8;
  const int adst = t * 8;

#define ISSUE_A(k_, ab_)                                                      \
  do {                                                                        \
    _Pragma("unroll")                                                         \
    for (int i = 0; i < 2; ++i)                                               \
      gload16(asrc[i] + (k_), &sA[(ab_) * 8192 + i * 4096 + adst]);           \
  } while (0)
#define ISSUE_B(k_, bo_)                                                      \
  do {                                                                        \
    _Pragma("unroll")                                                         \
    for (int i = 0; i < 2; ++i)                                               \
      gload16(bsrc[i] + (k_), &sB[(bo_) + i * 4096 + adst]);                  \
  } while (0)

  const int wr = (wid >> 1) * 32, wc = (wid & 1) * 64;
  const int lrow = lane & 15, grp = lane >> 4;

  f32x4 acc[2][4];
#pragma unroll
  for (int m = 0; m < 2; ++m)
#pragma unroll
    for (int n = 0; n < 4; ++n)
#pragma unroll
      for (int i = 0; i < 4; ++i) acc[m][n][i] = 0.f;

#define COMPUTE(ab_, bo_)                                                     \
  do {                                                                        \
    _Pragma("unroll")                                                         \
    for (int ks = 0; ks < 2; ++ks) {                                          \
      const int ch = ks * 4 + grp;                                            \
      bf16x8 av[2], bv[4];                                                    \
      _Pragma("unroll")                                                       \
      for (int m = 0; m < 2; ++m) {                                           \
        const int r = wr + m * 16 + lrow;                                     \
        av[m] = *(const bf16x8*)&sA[(ab_) * 8192 + r * 64 + ((ch ^ (r & 7)) << 3)]; \
      }                                                                       \
      _Pragma("unroll")                                                       \
      for (int n = 0; n < 4; ++n) {                                           \
        const int r = wc + n * 16 + lrow;                                     \
        bv[n] = *(const bf16x8*)&sB[(bo_) + r * 64 + ((ch ^ (r & 7)) << 3)];  \
      }                                                                       \
      _Pragma("unroll")                                                       \
      for (int m = 0; m < 2; ++m)                                             \
        _Pragma("unroll")                                                     \
        for (int n = 0; n < 4; ++n)                                           \
          acc[m][n] = __builtin_amdgcn_mfma_f32_16x16x32_bf16(av[m], bv[n], acc[m][n], 0, 0, 0); \
    }                                                                         \
  } while (0)

  ISSUE_A(0, 0);
  ISSUE_B(0, 0);
  SBAR0();
  ISSUE_B(64, 8192);
  SBAR0();
  WAIT_VM(2);
  __builtin_amdgcn_s_barrier();

  int bb0 = 0, bb1 = 8192, bb2 = 16384;
  for (int k = 0; k < NK - 2; ++k) {
    ISSUE_A((k + 1) * 64, (k + 1) & 1);
    SBAR0();
    ISSUE_B((k + 2) * 64, bb2);
    SBAR0();
    COMPUTE(k & 1, bb0);
    WAIT_VM(2);
    __builtin_amdgcn_s_barrier();
    int tmp = bb0; bb0 = bb1; bb1 = bb2; bb2 = tmp;
  }
  ISSUE_A((NK - 1) * 64, (NK - 1) & 1);
  SBAR0();
  COMPUTE((NK - 2) & 1, bb0);
  WAIT_VM(0);
  __builtin_amdgcn_s_barrier();
  { int tmp = bb0; bb0 = bb1; bb1 = bb2; bb2 = tmp; }
  COMPUTE((NK - 1) & 1, bb0);
#undef ISSUE_A
#undef ISSUE_B
#undef COMPUTE

#pragma unroll
  for (int m = 0; m < 2; ++m) {
#pragma unroll
    for (int i = 0; i < 4; ++i) {
      const int rl = wr + m * 16 + grp * 4 + i;
      if (rl >= mguard) continue;
      if (is_exp) {
        const int row = rowbase + rl;
        const float scl = entry_gate[row];
        bf16* orow = out_e + (size_t)row * CDIM + n0;
#pragma unroll
        for (int n = 0; n < 4; ++n)
          orow[wc + n * 16 + lrow] = (bf16)(acc[m][n][i] * scl);
      } else {
        float* orow = out + (size_t)(rowbase + rl) * CDIM + n0;
#pragma unroll
        for (int n = 0; n < 4; ++n)
          orow[wc + n * 16 + lrow] = acc[m][n][i];
      }
    }
  }
}

// ---------------- combine ----------------
__global__ void combine_kernel(float* __restrict__ out,
                               const bf16* __restrict__ out_e,
                               const int* __restrict__ entry_pos) {
  int tid = blockIdx.x * blockDim.x + threadIdx.x;
  int n = tid >> 8;
  int c4 = tid & 255;
  int p0 = entry_pos[2 * n];
  int p1 = entry_pos[2 * n + 1];
  float4 v = ((const float4*)out)[tid];
  ushort4 a = *(const ushort4*)((const u16*)out_e + (size_t)p0 * CDIM + c4 * 4);
  ushort4 b = *(const ushort4*)((const u16*)out_e + (size_t)p1 * CDIM + c4 * 4);
  v.x += fromb(a.x) + fromb(b.x);
  v.y += fromb(a.y) + fromb(b.y);
  v.z += fromb(a.z) + fromb(b.z);
  v.w += fromb(a.w) + fromb(b.w);
  ((float4*)out)[tid] = v;
}

extern "C" void kernel_launch(void* const* d_in, const int* in_sizes, int n_in,
                              void* d_out, int out_size, void* d_ws, size_t ws_size,
                              hipStream_t stream) {
  const float* x   = (const float*)d_in[0];
  const float* rw  = (const float*)d_in[1];
  const float* guw = (const float*)d_in[2];
  const float* dw  = (const float*)d_in[3];
  const float* sgw = (const float*)d_in[4];
  const float* suw = (const float*)d_in[5];
  const float* sdw = (const float*)d_in[6];
  float* out = (float*)d_out;
  char* ws = (char*)d_ws;
  const size_t MB = 1048576;

  int*   sel         = (int*)(ws + 0);
  float* gatew       = (float*)(ws + 16384);
  int*   counts      = (int*)(ws + 32768);
  int*   offsets     = (int*)(ws + 32832);
  int*   ntiles      = (int*)(ws + 32960);
  int*   tab128      = (int*)(ws + 33024);
  int*   entry_token = (int*)(ws + 33664);
  float* entry_gate  = (float*)(ws + 50048);
  int*   entry_pos   = (int*)(ws + 66432);

  bf16* xb    = (bf16*)(ws + 82816);                 // 4 MB
  bf16* h_exp = (bf16*)(ws + 82816 + 4 * MB);        // 8 MB
  bf16* h_sh  = (bf16*)(ws + 82816 + 12 * MB);       // 8 MB
  bf16* sgw_b = (bf16*)(ws + 82816 + 20 * MB);       // 4 MB
  bf16* suw_b = (bf16*)(ws + 82816 + 24 * MB);       // 4 MB
  bf16* guw_b = (bf16*)(ws + 82816 + 28 * MB);       // 64 MB
  bf16* dw_b  = (bf16*)(ws + 82816 + 92 * MB);       // 32 MB
  bf16* sdw_b = (bf16*)(ws + 82816 + 124 * MB);      // 4 MB (peak ~128 MB)
  bf16* out_e = sgw_b;                               // alias (dead after gu9x)

  // 1) routing + fused x conversion
  router_kernel<<<N_TOK / 4, 256, 0, stream>>>(x, rw, xb, sel, gatew);

  // 2) guw transpose-convert + small converts + scan/scatter (one launch)
  prep_kernel<<<PREP_NWG, 256, 0, stream>>>(guw, sgw, suw, sdw,
                                            guw_b, sgw_b, suw_b, sdw_b,
                                            sel, gatew, counts, offsets, tab128,
                                            ntiles, entry_token, entry_gate, entry_pos);

  // 3) gate+up GEMM + SwiGLU, with dw transpose-convert in trailing blocks
  gu9x<<<GU9X_NWG, 512, 0, stream>>>(xb, guw_b, sgw_b, suw_b, h_exp, h_sh,
                                     counts, offsets, entry_token, tab128, ntiles,
                                     dw, dw_b);

  // 4) down GEMM (expert + shared)
  dn9<<<DN_NWG, 512, 0, stream>>>(h_exp, h_sh, dw_b, sdw_b, entry_gate, out_e, out,
                                  counts, offsets, tab128, ntiles);

  // 5) add gated expert contributions
  combine_kernel<<<(N_TOK * CDIM / 4) / 256, 256, 0, stream>>>(out, out_e, entry_pos);
}